// Round 5
// baseline (258.337 us; speedup 1.0000x reference)
//
#include <hip/hip_runtime.h>
#include <stdint.h>

typedef float f32x4 __attribute__((ext_vector_type(4)));
typedef __bf16 bf16x8 __attribute__((ext_vector_type(8)));
typedef uint32_t u32a  __attribute__((may_alias));
typedef uint2    u2a   __attribute__((may_alias));
typedef uint4    u4a   __attribute__((may_alias));

__device__ __forceinline__ ushort f2b(float f) {
  uint32_t u = __builtin_bit_cast(uint32_t, f);
  u += 0x7FFFu + ((u >> 16) & 1u);   // round-to-nearest-even
  return (ushort)(u >> 16);
}
__device__ __forceinline__ uint32_t b16(uint32_t u) {  // fp32 bits -> bf16 bits (RNE)
  u += 0x7FFFu + ((u >> 16) & 1u);
  return u >> 16;
}

__device__ __forceinline__ bf16x8 ld_frag(const ushort* p) {
  u4a u = *(const u4a*)p;            // ds_read_b128
  return __builtin_bit_cast(bf16x8, u);
}

// 8 fp32 -> 8 bf16 packed (two dwordx4 loads + RNE pack)
__device__ __forceinline__ u4a cvt8(const float* p) {
  u4a a = *(const u4a*)p, b = *(const u4a*)(p + 4), o;
  o.x = b16(a.x) | (b16(a.y) << 16);
  o.y = b16(a.z) | (b16(a.w) << 16);
  o.z = b16(b.x) | (b16(b.y) << 16);
  o.w = b16(b.z) | (b16(b.w) << 16);
  return o;
}

__device__ __forceinline__ void load_lds16(const void* g, void* l) {
  __builtin_amdgcn_global_load_lds(
      (const __attribute__((address_space(1))) uint32_t*)g,
      (__attribute__((address_space(3))) uint32_t*)l, 16, 0, 0);
}

// ---------------------------------------------------------------------------
// fp32 -> bf16 one-shot convert: x (3145728) then wq/wk/wv/wo (589824 each).
// ---------------------------------------------------------------------------
__global__ __launch_bounds__(256) void convert_kernel(
    const float* __restrict__ x,  const float* __restrict__ wq,
    const float* __restrict__ wk, const float* __restrict__ wv,
    const float* __restrict__ wo,
    ushort* __restrict__ xb,  ushort* __restrict__ wqb,
    ushort* __restrict__ wkb, ushort* __restrict__ wvb,
    ushort* __restrict__ wob)
{
  const size_t NX = 3145728, NW = 589824;
  size_t idx = ((size_t)blockIdx.x * 256 + threadIdx.x) * 8;
  const float* src; ushort* dst; size_t off;
  if      (idx < NX)          { src = x;  dst = xb;  off = idx; }
  else if (idx < NX + NW)     { src = wq; dst = wqb; off = idx - NX; }
  else if (idx < NX + 2 * NW) { src = wk; dst = wkb; off = idx - NX - NW; }
  else if (idx < NX + 3 * NW) { src = wv; dst = wvb; off = idx - NX - 2 * NW; }
  else                        { src = wo; dst = wob; off = idx - NX - 3 * NW; }
  *(u4a*)(dst + off) = cvt8(src + off);
}

// ---------------------------------------------------------------------------
// QKV: C[M,N] = A[M,K]*B[N,K]^T, all bf16, fp32 acc. z selects weight+dest.
// z=0 -> Q row-major, z=1 -> K row-major, z=2 -> V written TRANSPOSED to
// Vt[b][h][dv][s] (free transpose for the attention PV B-operand).
// BM=BN=128, BK=32, 256 threads; m97-style global_load_lds staging.
// ---------------------------------------------------------------------------
__global__ __launch_bounds__(256) void gemm_qkv(
    const ushort* __restrict__ A,
    const ushort* __restrict__ B0, const ushort* __restrict__ B1,
    const ushort* __restrict__ B2,
    ushort* __restrict__ Qo, ushort* __restrict__ Ko, ushort* __restrict__ Vt,
    int M, int N, int K)
{
  const ushort* B = blockIdx.z == 0 ? B0 : (blockIdx.z == 1 ? B1 : B2);
  const int m0 = blockIdx.x * 128, n0 = blockIdx.y * 128;
  __shared__ ushort As[128 * 32];   // linear chunk order (global_load_lds layout)
  __shared__ ushort Bs[128 * 32];
  const int tid = threadIdx.x, wave = tid >> 6, lane = tid & 63;
  const int quad = lane >> 4, l16 = lane & 15;
  const int mw = (wave & 1) * 64, nw = (wave >> 1) * 64;
  f32x4 acc[4][4] = {};

  for (int k0 = 0; k0 < K; k0 += 32) {
    // 512 chunks of 16B per tile; chunk c -> row c>>2, col (c&3)*8
#pragma unroll
    for (int i = 0; i < 2; ++i) {
      int c = i * 256 + tid;
      int r = c >> 2, col = (c & 3) * 8;
      load_lds16(A + (size_t)(m0 + r) * K + k0 + col, As + (size_t)(i * 256 + wave * 64) * 8);
      load_lds16(B + (size_t)(n0 + r) * K + k0 + col, Bs + (size_t)(i * 256 + wave * 64) * 8);
    }
    __syncthreads();
    bf16x8 af[4], bfr[4];
#pragma unroll
    for (int i = 0; i < 4; ++i) af[i]  = ld_frag(As + (mw + i * 16 + l16) * 32 + quad * 8);
#pragma unroll
    for (int j = 0; j < 4; ++j) bfr[j] = ld_frag(Bs + (nw + j * 16 + l16) * 32 + quad * 8);
#pragma unroll
    for (int i = 0; i < 4; ++i)
#pragma unroll
      for (int j = 0; j < 4; ++j)
        acc[i][j] = __builtin_amdgcn_mfma_f32_16x16x32_bf16(af[i], bfr[j], acc[i][j], 0, 0, 0);
    __syncthreads();
  }
  // C/D layout: col=lane&15 (N), row=quad*4+reg (M)
  if (blockIdx.z < 2) {
    ushort* C = blockIdx.z == 0 ? Qo : Ko;
#pragma unroll
    for (int i = 0; i < 4; ++i)
#pragma unroll
      for (int j = 0; j < 4; ++j)
#pragma unroll
        for (int r = 0; r < 4; ++r) {
          int row = m0 + mw + i * 16 + quad * 4 + r;
          int col = n0 + nw + j * 16 + l16;
          C[(size_t)row * N + col] = f2b(acc[i][j][r]);
        }
  } else {
    // Vt[b][h][dv][s]: col -> (h=col>>6, dv=col&63); token -> (b=t>>11, s=t&2047)
#pragma unroll
    for (int i = 0; i < 4; ++i)
#pragma unroll
      for (int j = 0; j < 4; ++j) {
        int col = n0 + nw + j * 16 + l16;
        int h = col >> 6, dv = col & 63;
        int t = m0 + mw + i * 16 + quad * 4;
        int b = t >> 11, s = t & 2047;
        u2a pw;
        pw.x = (uint32_t)f2b(acc[i][j][0]) | ((uint32_t)f2b(acc[i][j][1]) << 16);
        pw.y = (uint32_t)f2b(acc[i][j][2]) | ((uint32_t)f2b(acc[i][j][3]) << 16);
        *(u2a*)(Vt + (((size_t)b * 12 + h) * 64 + dv) * 2048 + s) = pw;
      }
  }
}

// ---------------------------------------------------------------------------
// Output projection: C[M,N](fp32) = A[M,K](bf16) * B[N,K]^T(bf16).
// ---------------------------------------------------------------------------
__global__ __launch_bounds__(256) void gemm_out(
    const ushort* __restrict__ A, const ushort* __restrict__ B,
    float* __restrict__ C, int M, int N, int K)
{
  const int m0 = blockIdx.x * 128, n0 = blockIdx.y * 128;
  __shared__ ushort As[128 * 32];
  __shared__ ushort Bs[128 * 32];
  const int tid = threadIdx.x, wave = tid >> 6, lane = tid & 63;
  const int quad = lane >> 4, l16 = lane & 15;
  const int mw = (wave & 1) * 64, nw = (wave >> 1) * 64;
  f32x4 acc[4][4] = {};

  for (int k0 = 0; k0 < K; k0 += 32) {
#pragma unroll
    for (int i = 0; i < 2; ++i) {
      int c = i * 256 + tid;
      int r = c >> 2, col = (c & 3) * 8;
      load_lds16(A + (size_t)(m0 + r) * K + k0 + col, As + (size_t)(i * 256 + wave * 64) * 8);
      load_lds16(B + (size_t)(n0 + r) * K + k0 + col, Bs + (size_t)(i * 256 + wave * 64) * 8);
    }
    __syncthreads();
    bf16x8 af[4], bfr[4];
#pragma unroll
    for (int i = 0; i < 4; ++i) af[i]  = ld_frag(As + (mw + i * 16 + l16) * 32 + quad * 8);
#pragma unroll
    for (int j = 0; j < 4; ++j) bfr[j] = ld_frag(Bs + (nw + j * 16 + l16) * 32 + quad * 8);
#pragma unroll
    for (int i = 0; i < 4; ++i)
#pragma unroll
      for (int j = 0; j < 4; ++j)
        acc[i][j] = __builtin_amdgcn_mfma_f32_16x16x32_bf16(af[i], bfr[j], acc[i][j], 0, 0, 0);
    __syncthreads();
  }
#pragma unroll
  for (int i = 0; i < 4; ++i)
#pragma unroll
    for (int j = 0; j < 4; ++j)
#pragma unroll
      for (int r = 0; r < 4; ++r) {
        int row = m0 + mw + i * 16 + quad * 4 + r;
        int col = n0 + nw + j * 16 + l16;
        C[(size_t)row * N + col] = acc[i][j][r];
      }
}

// ---------------------------------------------------------------------------
// Causal flash attention. Q/K row-major (b,s,h*64) bf16; V pre-transposed
// Vt[b][h][dv][s]. Block: 64 q rows (4 waves x 16 q), K-tiles of 128.
// Computes S^T = K*Q^T so P packs to LDS with b64 writes (kk-contiguous rows).
// ---------------------------------------------------------------------------
__global__ __launch_bounds__(256) void attn_kernel(
    const ushort* __restrict__ Qb, const ushort* __restrict__ Kb,
    const ushort* __restrict__ Vt, ushort* __restrict__ Ob)
{
  const int S = 2048, DM = 768;
  const int qt = blockIdx.x, h = blockIdx.y, bb = blockIdx.z;
  const int q0 = qt * 64;
  const ushort* Qp  = Qb + (size_t)bb * S * DM + h * 64;
  const ushort* Kp  = Kb + (size_t)bb * S * DM + h * 64;
  const ushort* Vth = Vt + ((size_t)bb * 12 + h) * 64 * 2048;   // [dv][s]
  ushort* Op        = Ob + (size_t)bb * S * DM + h * 64;

  __shared__ ushort Ks[128 * 72];     // [kk][dk], pad 64->72
  __shared__ ushort Vs[64 * 136];     // [dv][kk], pad 128->136
  __shared__ ushort Ps[4][16 * 136];  // per-wave P[q][kk], pad 128->136

  const int tid = threadIdx.x, wave = tid >> 6, lane = tid & 63;
  const int quad = lane >> 4, l16 = lane & 15;
  const int qg = q0 + wave * 16 + l16;   // this lane's q row (stats / B-frag col)
  const float LOG2E = 1.44269504f;
  const float NEG_BIG = -1.0e30f;

  // Q fragments (B operand of S^T = K*Q^T): lane n=q reads 8 consecutive dk
  bf16x8 bq0 = ld_frag(Qp + (size_t)qg * DM + quad * 8);
  bf16x8 bq1 = ld_frag(Qp + (size_t)qg * DM + 32 + quad * 8);

  f32x4 acc_o[4] = {};
  float m_run = NEG_BIG, l_run = 0.0f;
  const int nkt = (q0 + 63) / 128 + 1;

  for (int kt = 0; kt < nkt; ++kt) {
    const int kk0 = kt * 128;
    // stage K tile: 1024 chunks of 8 bf16; chunk c -> row c>>3, col (c&7)*8
#pragma unroll
    for (int i = 0; i < 4; ++i) {
      int c = i * 256 + tid;
      int r = c >> 3, col = (c & 7) * 8;
      *(u4a*)(Ks + r * 72 + col) = *(const u4a*)(Kp + (size_t)(kk0 + r) * DM + col);
    }
    // stage V tile from pre-transposed Vt: chunk c -> dv c>>4, kk (c&15)*8
#pragma unroll
    for (int i = 0; i < 4; ++i) {
      int c = i * 256 + tid;
      int dv = c >> 4, kc = (c & 15) * 8;
      *(u4a*)(Vs + dv * 136 + kc) = *(const u4a*)(Vth + (size_t)dv * 2048 + kk0 + kc);
    }
    __syncthreads();

    // S^T strip: this wave's 16 q cols x 128 kk rows = 8 tiles
    f32x4 sacc[8] = {};
#pragma unroll
    for (int tt = 0; tt < 8; ++tt) {
      bf16x8 ak0 = ld_frag(Ks + (tt * 16 + l16) * 72 + quad * 8);
      bf16x8 ak1 = ld_frag(Ks + (tt * 16 + l16) * 72 + 32 + quad * 8);
      sacc[tt] = __builtin_amdgcn_mfma_f32_16x16x32_bf16(ak0, bq0, sacc[tt], 0, 0, 0);
      sacc[tt] = __builtin_amdgcn_mfma_f32_16x16x32_bf16(ak1, bq1, sacc[tt], 0, 0, 0);
    }

    // scale + causal mask (only last tile can straddle the diagonal)
    const bool domask = (kt == nkt - 1);
    float sv[8][4];
    float mt = NEG_BIG;
#pragma unroll
    for (int tt = 0; tt < 8; ++tt)
#pragma unroll
      for (int r = 0; r < 4; ++r) {
        float s = sacc[tt][r] * 0.125f;   // 1/sqrt(64)
        if (domask) {
          int kkg = kk0 + tt * 16 + quad * 4 + r;
          if (kkg > qg) s = NEG_BIG;
        }
        sv[tt][r] = s;
        mt = fmaxf(mt, s);
      }
    mt = fmaxf(mt, __shfl_xor(mt, 16, 64));
    mt = fmaxf(mt, __shfl_xor(mt, 32, 64));
    float mnew = fmaxf(m_run, mt);
    float alpha = exp2f((m_run - mnew) * LOG2E);
    float lsum = 0.0f;
#pragma unroll
    for (int tt = 0; tt < 8; ++tt) {
      float p0 = exp2f((sv[tt][0] - mnew) * LOG2E);
      float p1 = exp2f((sv[tt][1] - mnew) * LOG2E);
      float p2 = exp2f((sv[tt][2] - mnew) * LOG2E);
      float p3 = exp2f((sv[tt][3] - mnew) * LOG2E);
      lsum += (p0 + p1) + (p2 + p3);
      u2a pw;
      pw.x = (uint32_t)f2b(p0) | ((uint32_t)f2b(p1) << 16);
      pw.y = (uint32_t)f2b(p2) | ((uint32_t)f2b(p3) << 16);
      // P[q=l16][kk = tt*16 + quad*4 .. +3] — 4 consecutive kk -> one b64 write
      *(u2a*)(&Ps[wave][l16 * 136 + tt * 16 + quad * 4]) = pw;
    }
    // Ps is per-wave data: drain LDS writes + forbid compile-time reordering.
    asm volatile("s_waitcnt lgkmcnt(0)" ::: "memory");
    lsum += __shfl_xor(lsum, 16, 64);
    lsum += __shfl_xor(lsum, 32, 64);
    l_run = l_run * alpha + lsum;
    m_run = mnew;

    // rescale O: O rows are q = quad*4+reg, alpha lives at lane l16==q
    float ar0 = __shfl(alpha, quad * 4 + 0, 64);
    float ar1 = __shfl(alpha, quad * 4 + 1, 64);
    float ar2 = __shfl(alpha, quad * 4 + 2, 64);
    float ar3 = __shfl(alpha, quad * 4 + 3, 64);
#pragma unroll
    for (int ct = 0; ct < 4; ++ct) {
      acc_o[ct][0] *= ar0; acc_o[ct][1] *= ar1;
      acc_o[ct][2] *= ar2; acc_o[ct][3] *= ar3;
    }

    // O += P*V : A=P (kk-contiguous rows), B=V via Vs[dv][kk]
#pragma unroll
    for (int ks = 0; ks < 4; ++ks) {
      bf16x8 ap = ld_frag(&Ps[wave][l16 * 136 + ks * 32 + quad * 8]);
#pragma unroll
      for (int ct = 0; ct < 4; ++ct) {
        bf16x8 bv = ld_frag(Vs + (size_t)(ct * 16 + l16) * 136 + ks * 32 + quad * 8);
        acc_o[ct] = __builtin_amdgcn_mfma_f32_16x16x32_bf16(ap, bv, acc_o[ct], 0, 0, 0);
      }
    }
    __syncthreads();   // protect Ks/Vs before next iteration restages
  }

  // epilogue: normalize by 1/l (re-indexed to O's row mapping) and store
  float inv0 = 1.0f / __shfl(l_run, quad * 4 + 0, 64);
  float inv1 = 1.0f / __shfl(l_run, quad * 4 + 1, 64);
  float inv2 = 1.0f / __shfl(l_run, quad * 4 + 2, 64);
  float inv3 = 1.0f / __shfl(l_run, quad * 4 + 3, 64);
#pragma unroll
  for (int ct = 0; ct < 4; ++ct) {
    int col = ct * 16 + l16;
    int srow = q0 + wave * 16 + quad * 4;
    Op[(size_t)(srow + 0) * DM + col] = f2b(acc_o[ct][0] * inv0);
    Op[(size_t)(srow + 1) * DM + col] = f2b(acc_o[ct][1] * inv1);
    Op[(size_t)(srow + 2) * DM + col] = f2b(acc_o[ct][2] * inv2);
    Op[(size_t)(srow + 3) * DM + col] = f2b(acc_o[ct][3] * inv3);
  }
}

// ---------------------------------------------------------------------------
extern "C" void kernel_launch(void* const* d_in, const int* in_sizes, int n_in,
                              void* d_out, int out_size, void* d_ws, size_t ws_size,
                              hipStream_t stream) {
  (void)in_sizes; (void)n_in; (void)out_size; (void)ws_size;
  const float* x  = (const float*)d_in[0];
  const float* wq = (const float*)d_in[1];
  const float* wk = (const float*)d_in[2];
  const float* wv = (const float*)d_in[3];
  const float* wo = (const float*)d_in[4];

  const size_t NT = (size_t)4096 * 768;   // tokens x d_model
  const size_t NW = (size_t)768 * 768;
  ushort* xb   = (ushort*)d_ws;           // reused as Abuf after QKV GEMM
  ushort* Qbuf = xb + NT;
  ushort* Kbuf = Qbuf + NT;
  ushort* Vt   = Kbuf + NT;               // (b, h, dv, s)
  ushort* wqb  = Vt + NT;
  ushort* wkb  = wqb + NW;
  ushort* wvb  = wkb + NW;
  ushort* wob  = wvb + NW;
  ushort* Abuf = xb;                      // lifetime-disjoint reuse

  // fp32 -> bf16 (x + all weights), 8 elems/thread
  convert_kernel<<<2688, 256, 0, stream>>>(x, wq, wk, wv, wo,
                                           xb, wqb, wkb, wvb, wob);
  // Q/K/V projections (z picks weight & dest; V lands transposed in Vt)
  gemm_qkv<<<dim3(32, 6, 3), 256, 0, stream>>>(
      xb, wqb, wkb, wvb, Qbuf, Kbuf, Vt, 4096, 768, 768);
  // causal flash attention
  attn_kernel<<<dim3(32, 12, 2), 256, 0, stream>>>(Qbuf, Kbuf, Vt, Abuf);
  // output projection (fp32 out)
  gemm_out<<<dim3(32, 6), 256, 0, stream>>>(
      Abuf, wob, (float*)d_out, 4096, 768, 768);
}

// Round 6
// 203.169 us; speedup vs baseline: 1.2715x; 1.2715x over previous
//
#include <hip/hip_runtime.h>
#include <stdint.h>

typedef float f32x4 __attribute__((ext_vector_type(4)));
typedef __bf16 bf16x8 __attribute__((ext_vector_type(8)));
typedef uint32_t u32a  __attribute__((may_alias));
typedef uint2    u2a   __attribute__((may_alias));
typedef uint4    u4a   __attribute__((may_alias));

#define VS 2064   // Vt row stride in elements (2048 + 16: breaks 4KB L2 aliasing)

__device__ __forceinline__ ushort f2b(float f) {
  uint32_t u = __builtin_bit_cast(uint32_t, f);
  u += 0x7FFFu + ((u >> 16) & 1u);   // round-to-nearest-even
  return (ushort)(u >> 16);
}
__device__ __forceinline__ uint32_t b16(uint32_t u) {  // fp32 bits -> bf16 bits (RNE)
  u += 0x7FFFu + ((u >> 16) & 1u);
  return u >> 16;
}

__device__ __forceinline__ bf16x8 ld_frag(const ushort* p) {
  u4a u = *(const u4a*)p;            // ds_read_b128
  return __builtin_bit_cast(bf16x8, u);
}

// 8 fp32 -> 8 bf16 packed (two dwordx4 loads + RNE pack)
__device__ __forceinline__ u4a cvt8(const float* p) {
  u4a a = *(const u4a*)p, b = *(const u4a*)(p + 4), o;
  o.x = b16(a.x) | (b16(a.y) << 16);
  o.y = b16(a.z) | (b16(a.w) << 16);
  o.z = b16(b.x) | (b16(b.y) << 16);
  o.w = b16(b.z) | (b16(b.w) << 16);
  return o;
}

__device__ __forceinline__ void load_lds16(const void* g, void* l) {
  __builtin_amdgcn_global_load_lds(
      (const __attribute__((address_space(1))) uint32_t*)g,
      (__attribute__((address_space(3))) uint32_t*)l, 16, 0, 0);
}

// ---------------------------------------------------------------------------
// fp32 -> bf16 one-shot convert: x (3145728) then wq/wk/wv/wo (589824 each).
// ---------------------------------------------------------------------------
__global__ __launch_bounds__(256) void convert_kernel(
    const float* __restrict__ x,  const float* __restrict__ wq,
    const float* __restrict__ wk, const float* __restrict__ wv,
    const float* __restrict__ wo,
    ushort* __restrict__ xb,  ushort* __restrict__ wqb,
    ushort* __restrict__ wkb, ushort* __restrict__ wvb,
    ushort* __restrict__ wob)
{
  const size_t NX = 3145728, NW = 589824;
  size_t idx = ((size_t)blockIdx.x * 256 + threadIdx.x) * 8;
  const float* src; ushort* dst; size_t off;
  if      (idx < NX)          { src = x;  dst = xb;  off = idx; }
  else if (idx < NX + NW)     { src = wq; dst = wqb; off = idx - NX; }
  else if (idx < NX + 2 * NW) { src = wk; dst = wkb; off = idx - NX - NW; }
  else if (idx < NX + 3 * NW) { src = wv; dst = wvb; off = idx - NX - 2 * NW; }
  else                        { src = wo; dst = wob; off = idx - NX - 3 * NW; }
  *(u4a*)(dst + off) = cvt8(src + off);
}

// ---------------------------------------------------------------------------
// QKV: C[M,N] = A[M,K]*B[N,K]^T, all bf16, fp32 acc. z selects weight+dest.
// z=0 -> Q row-major, z=1 -> K row-major, z=2 -> V written TRANSPOSED to
// Vt[b][h][dv][s] with padded row stride VS (free transpose for attention PV).
// BM=BN=128, BK=32, 256 threads; m97-style global_load_lds staging.
// ---------------------------------------------------------------------------
__global__ __launch_bounds__(256) void gemm_qkv(
    const ushort* __restrict__ A,
    const ushort* __restrict__ B0, const ushort* __restrict__ B1,
    const ushort* __restrict__ B2,
    ushort* __restrict__ Qo, ushort* __restrict__ Ko, ushort* __restrict__ Vt,
    int M, int N, int K)
{
  const ushort* B = blockIdx.z == 0 ? B0 : (blockIdx.z == 1 ? B1 : B2);
  const int m0 = blockIdx.x * 128, n0 = blockIdx.y * 128;
  __shared__ ushort As[128 * 32];   // linear chunk order (global_load_lds layout)
  __shared__ ushort Bs[128 * 32];
  const int tid = threadIdx.x, wave = tid >> 6, lane = tid & 63;
  const int quad = lane >> 4, l16 = lane & 15;
  const int mw = (wave & 1) * 64, nw = (wave >> 1) * 64;
  f32x4 acc[4][4] = {};

  for (int k0 = 0; k0 < K; k0 += 32) {
    // 512 chunks of 16B per tile; chunk c -> row c>>2, col (c&3)*8
#pragma unroll
    for (int i = 0; i < 2; ++i) {
      int c = i * 256 + tid;
      int r = c >> 2, col = (c & 3) * 8;
      load_lds16(A + (size_t)(m0 + r) * K + k0 + col, As + (size_t)(i * 256 + wave * 64) * 8);
      load_lds16(B + (size_t)(n0 + r) * K + k0 + col, Bs + (size_t)(i * 256 + wave * 64) * 8);
    }
    __syncthreads();
    bf16x8 af[4], bfr[4];
#pragma unroll
    for (int i = 0; i < 4; ++i) af[i]  = ld_frag(As + (mw + i * 16 + l16) * 32 + quad * 8);
#pragma unroll
    for (int j = 0; j < 4; ++j) bfr[j] = ld_frag(Bs + (nw + j * 16 + l16) * 32 + quad * 8);
#pragma unroll
    for (int i = 0; i < 4; ++i)
#pragma unroll
      for (int j = 0; j < 4; ++j)
        acc[i][j] = __builtin_amdgcn_mfma_f32_16x16x32_bf16(af[i], bfr[j], acc[i][j], 0, 0, 0);
    __syncthreads();
  }
  // C/D layout: col=lane&15 (N), row=quad*4+reg (M)
  if (blockIdx.z < 2) {
    ushort* C = blockIdx.z == 0 ? Qo : Ko;
#pragma unroll
    for (int i = 0; i < 4; ++i)
#pragma unroll
      for (int j = 0; j < 4; ++j)
#pragma unroll
        for (int r = 0; r < 4; ++r) {
          int row = m0 + mw + i * 16 + quad * 4 + r;
          int col = n0 + nw + j * 16 + l16;
          C[(size_t)row * N + col] = f2b(acc[i][j][r]);
        }
  } else {
    // Vt[b][h][dv][s] (stride VS): col -> (h=col>>6, dv=col&63); t -> (b,s)
#pragma unroll
    for (int i = 0; i < 4; ++i)
#pragma unroll
      for (int j = 0; j < 4; ++j) {
        int col = n0 + nw + j * 16 + l16;
        int h = col >> 6, dv = col & 63;
        int t = m0 + mw + i * 16 + quad * 4;
        int b = t >> 11, s = t & 2047;
        u2a pw;
        pw.x = (uint32_t)f2b(acc[i][j][0]) | ((uint32_t)f2b(acc[i][j][1]) << 16);
        pw.y = (uint32_t)f2b(acc[i][j][2]) | ((uint32_t)f2b(acc[i][j][3]) << 16);
        *(u2a*)(Vt + (((size_t)b * 12 + h) * 64 + dv) * VS + s) = pw;
      }
  }
}

// ---------------------------------------------------------------------------
// Output projection: C[M,N](fp32) = A[M,K](bf16) * B[N,K]^T(bf16).
// ---------------------------------------------------------------------------
__global__ __launch_bounds__(256) void gemm_out(
    const ushort* __restrict__ A, const ushort* __restrict__ B,
    float* __restrict__ C, int M, int N, int K)
{
  const int m0 = blockIdx.x * 128, n0 = blockIdx.y * 128;
  __shared__ ushort As[128 * 32];
  __shared__ ushort Bs[128 * 32];
  const int tid = threadIdx.x, wave = tid >> 6, lane = tid & 63;
  const int quad = lane >> 4, l16 = lane & 15;
  const int mw = (wave & 1) * 64, nw = (wave >> 1) * 64;
  f32x4 acc[4][4] = {};

  for (int k0 = 0; k0 < K; k0 += 32) {
#pragma unroll
    for (int i = 0; i < 2; ++i) {
      int c = i * 256 + tid;
      int r = c >> 2, col = (c & 3) * 8;
      load_lds16(A + (size_t)(m0 + r) * K + k0 + col, As + (size_t)(i * 256 + wave * 64) * 8);
      load_lds16(B + (size_t)(n0 + r) * K + k0 + col, Bs + (size_t)(i * 256 + wave * 64) * 8);
    }
    __syncthreads();
    bf16x8 af[4], bfr[4];
#pragma unroll
    for (int i = 0; i < 4; ++i) af[i]  = ld_frag(As + (mw + i * 16 + l16) * 32 + quad * 8);
#pragma unroll
    for (int j = 0; j < 4; ++j) bfr[j] = ld_frag(Bs + (nw + j * 16 + l16) * 32 + quad * 8);
#pragma unroll
    for (int i = 0; i < 4; ++i)
#pragma unroll
      for (int j = 0; j < 4; ++j)
        acc[i][j] = __builtin_amdgcn_mfma_f32_16x16x32_bf16(af[i], bfr[j], acc[i][j], 0, 0, 0);
    __syncthreads();
  }
#pragma unroll
  for (int i = 0; i < 4; ++i)
#pragma unroll
    for (int j = 0; j < 4; ++j)
#pragma unroll
      for (int r = 0; r < 4; ++r) {
        int row = m0 + mw + i * 16 + quad * 4 + r;
        int col = n0 + nw + j * 16 + l16;
        C[(size_t)row * N + col] = acc[i][j][r];
      }
}

// ---------------------------------------------------------------------------
// Causal flash attention, PAIR-BALANCED: block x = pair p handles q-tiles
// {p, 31-p} sequentially -> every block ~18 K-tile-units (uniform load).
// Q/K row-major (b,s,768) bf16; V pre-transposed Vt[b][h][dv][s] stride VS.
// Per strip: 64 q rows (4 waves x 16 q), K-tiles of 128, S^T = K*Q^T form.
// ---------------------------------------------------------------------------
__global__ __launch_bounds__(256) void attn_kernel(
    const ushort* __restrict__ Qb, const ushort* __restrict__ Kb,
    const ushort* __restrict__ Vt, ushort* __restrict__ Ob)
{
  const int S = 2048, DM = 768;
  const int pair = blockIdx.x, h = blockIdx.y, bb = blockIdx.z;
  const ushort* Qp  = Qb + (size_t)bb * S * DM + h * 64;
  const ushort* Kp  = Kb + (size_t)bb * S * DM + h * 64;
  const ushort* Vth = Vt + ((size_t)bb * 12 + h) * 64 * VS;   // [dv][s]
  ushort* Op        = Ob + (size_t)bb * S * DM + h * 64;

  __shared__ ushort Ks[128 * 72];     // [kk][dk], pad 64->72
  __shared__ ushort Vs[64 * 136];     // [dv][kk], pad 128->136
  __shared__ ushort Ps[4][16 * 136];  // per-wave P[q][kk], pad 128->136

  const int tid = threadIdx.x, wave = tid >> 6, lane = tid & 63;
  const int quad = lane >> 4, l16 = lane & 15;
  const float LOG2E = 1.44269504f;
  const float NEG_BIG = -1.0e30f;

  for (int sp = 0; sp < 2; ++sp) {
    const int qt = sp == 0 ? pair : 31 - pair;
    const int q0 = qt * 64;
    const int qg = q0 + wave * 16 + l16;   // this lane's q row

    // Q fragments (B operand of S^T = K*Q^T): lane n=q reads 8 consecutive dk
    bf16x8 bq0 = ld_frag(Qp + (size_t)qg * DM + quad * 8);
    bf16x8 bq1 = ld_frag(Qp + (size_t)qg * DM + 32 + quad * 8);

    f32x4 acc_o[4] = {};
    float m_run = NEG_BIG, l_run = 0.0f;
    const int nkt = (q0 + 63) / 128 + 1;

    for (int kt = 0; kt < nkt; ++kt) {
      const int kk0 = kt * 128;
      // stage K tile: 1024 chunks of 8 bf16; chunk c -> row c>>3, col (c&7)*8
#pragma unroll
      for (int i = 0; i < 4; ++i) {
        int c = i * 256 + tid;
        int r = c >> 3, col = (c & 7) * 8;
        *(u4a*)(Ks + r * 72 + col) = *(const u4a*)(Kp + (size_t)(kk0 + r) * DM + col);
      }
      // stage V tile from Vt: chunk c -> dv c>>4, kk (c&15)*8
#pragma unroll
      for (int i = 0; i < 4; ++i) {
        int c = i * 256 + tid;
        int dv = c >> 4, kc = (c & 15) * 8;
        *(u4a*)(Vs + dv * 136 + kc) = *(const u4a*)(Vth + (size_t)dv * VS + kk0 + kc);
      }
      __syncthreads();

      // S^T strip: this wave's 16 q cols x 128 kk rows = 8 tiles
      f32x4 sacc[8] = {};
#pragma unroll
      for (int tt = 0; tt < 8; ++tt) {
        bf16x8 ak0 = ld_frag(Ks + (tt * 16 + l16) * 72 + quad * 8);
        bf16x8 ak1 = ld_frag(Ks + (tt * 16 + l16) * 72 + 32 + quad * 8);
        sacc[tt] = __builtin_amdgcn_mfma_f32_16x16x32_bf16(ak0, bq0, sacc[tt], 0, 0, 0);
        sacc[tt] = __builtin_amdgcn_mfma_f32_16x16x32_bf16(ak1, bq1, sacc[tt], 0, 0, 0);
      }

      // scale + causal mask (only last tile can straddle the diagonal)
      const bool domask = (kt == nkt - 1);
      float sv[8][4];
      float mt = NEG_BIG;
#pragma unroll
      for (int tt = 0; tt < 8; ++tt)
#pragma unroll
        for (int r = 0; r < 4; ++r) {
          float s = sacc[tt][r] * 0.125f;   // 1/sqrt(64)
          if (domask) {
            int kkg = kk0 + tt * 16 + quad * 4 + r;
            if (kkg > qg) s = NEG_BIG;
          }
          sv[tt][r] = s;
          mt = fmaxf(mt, s);
        }
      mt = fmaxf(mt, __shfl_xor(mt, 16, 64));
      mt = fmaxf(mt, __shfl_xor(mt, 32, 64));
      float mnew = fmaxf(m_run, mt);
      float alpha = exp2f((m_run - mnew) * LOG2E);
      float lsum = 0.0f;
#pragma unroll
      for (int tt = 0; tt < 8; ++tt) {
        float p0 = exp2f((sv[tt][0] - mnew) * LOG2E);
        float p1 = exp2f((sv[tt][1] - mnew) * LOG2E);
        float p2 = exp2f((sv[tt][2] - mnew) * LOG2E);
        float p3 = exp2f((sv[tt][3] - mnew) * LOG2E);
        lsum += (p0 + p1) + (p2 + p3);
        u2a pw;
        pw.x = (uint32_t)f2b(p0) | ((uint32_t)f2b(p1) << 16);
        pw.y = (uint32_t)f2b(p2) | ((uint32_t)f2b(p3) << 16);
        // P[q=l16][kk = tt*16 + quad*4 .. +3] — one b64 write
        *(u2a*)(&Ps[wave][l16 * 136 + tt * 16 + quad * 4]) = pw;
      }
      // Ps is per-wave: drain own LDS writes, forbid compile-time reordering.
      asm volatile("s_waitcnt lgkmcnt(0)" ::: "memory");
      lsum += __shfl_xor(lsum, 16, 64);
      lsum += __shfl_xor(lsum, 32, 64);
      l_run = l_run * alpha + lsum;
      m_run = mnew;

      // rescale O: O rows are q = quad*4+reg, alpha lives at lane l16==q
      float ar0 = __shfl(alpha, quad * 4 + 0, 64);
      float ar1 = __shfl(alpha, quad * 4 + 1, 64);
      float ar2 = __shfl(alpha, quad * 4 + 2, 64);
      float ar3 = __shfl(alpha, quad * 4 + 3, 64);
#pragma unroll
      for (int ct = 0; ct < 4; ++ct) {
        acc_o[ct][0] *= ar0; acc_o[ct][1] *= ar1;
        acc_o[ct][2] *= ar2; acc_o[ct][3] *= ar3;
      }

      // O += P*V : A=P (kk-contiguous rows), B=V via Vs[dv][kk]
#pragma unroll
      for (int ks = 0; ks < 4; ++ks) {
        bf16x8 ap = ld_frag(&Ps[wave][l16 * 136 + ks * 32 + quad * 8]);
#pragma unroll
        for (int ct = 0; ct < 4; ++ct) {
          bf16x8 bv = ld_frag(Vs + (size_t)(ct * 16 + l16) * 136 + ks * 32 + quad * 8);
          acc_o[ct] = __builtin_amdgcn_mfma_f32_16x16x32_bf16(ap, bv, acc_o[ct], 0, 0, 0);
        }
      }
      __syncthreads();   // protect Ks/Vs before next restage (also inter-strip)
    }

    // epilogue: normalize by 1/l (re-indexed to O's row mapping) and store
    float inv0 = 1.0f / __shfl(l_run, quad * 4 + 0, 64);
    float inv1 = 1.0f / __shfl(l_run, quad * 4 + 1, 64);
    float inv2 = 1.0f / __shfl(l_run, quad * 4 + 2, 64);
    float inv3 = 1.0f / __shfl(l_run, quad * 4 + 3, 64);
#pragma unroll
    for (int ct = 0; ct < 4; ++ct) {
      int col = ct * 16 + l16;
      int srow = q0 + wave * 16 + quad * 4;
      Op[(size_t)(srow + 0) * DM + col] = f2b(acc_o[ct][0] * inv0);
      Op[(size_t)(srow + 1) * DM + col] = f2b(acc_o[ct][1] * inv1);
      Op[(size_t)(srow + 2) * DM + col] = f2b(acc_o[ct][2] * inv2);
      Op[(size_t)(srow + 3) * DM + col] = f2b(acc_o[ct][3] * inv3);
    }
  }
}

// ---------------------------------------------------------------------------
extern "C" void kernel_launch(void* const* d_in, const int* in_sizes, int n_in,
                              void* d_out, int out_size, void* d_ws, size_t ws_size,
                              hipStream_t stream) {
  (void)in_sizes; (void)n_in; (void)out_size; (void)ws_size;
  const float* x  = (const float*)d_in[0];
  const float* wq = (const float*)d_in[1];
  const float* wk = (const float*)d_in[2];
  const float* wv = (const float*)d_in[3];
  const float* wo = (const float*)d_in[4];

  const size_t NT = (size_t)4096 * 768;   // tokens x d_model
  const size_t NW = (size_t)768 * 768;
  const size_t NV = (size_t)24 * 64 * VS; // padded Vt
  ushort* xb   = (ushort*)d_ws;           // reused as Abuf after QKV GEMM
  ushort* Qbuf = xb + NT;
  ushort* Kbuf = Qbuf + NT;
  ushort* Vt   = Kbuf + NT;               // (b, h, dv, s) stride VS
  ushort* wqb  = Vt + NV;
  ushort* wkb  = wqb + NW;
  ushort* wvb  = wkb + NW;
  ushort* wob  = wvb + NW;
  ushort* Abuf = xb;                      // lifetime-disjoint reuse

  // fp32 -> bf16 (x + all weights), 8 elems/thread
  convert_kernel<<<2688, 256, 0, stream>>>(x, wq, wk, wv, wo,
                                           xb, wqb, wkb, wvb, wob);
  // Q/K/V projections (z picks weight & dest; V lands transposed in Vt)
  gemm_qkv<<<dim3(32, 6, 3), 256, 0, stream>>>(
      xb, wqb, wkb, wvb, Qbuf, Kbuf, Vt, 4096, 768, 768);
  // causal flash attention (pair-balanced)
  attn_kernel<<<dim3(16, 12, 2), 256, 0, stream>>>(Qbuf, Kbuf, Vt, Abuf);
  // output projection (fp32 out)
  gemm_out<<<dim3(32, 6), 256, 0, stream>>>(
      Abuf, wob, (float*)d_out, 4096, 768, 768);
}

// Round 7
// 175.342 us; speedup vs baseline: 1.4733x; 1.1587x over previous
//
#include <hip/hip_runtime.h>
#include <stdint.h>

typedef float f32x4 __attribute__((ext_vector_type(4)));
typedef __bf16 bf16x8 __attribute__((ext_vector_type(8)));
typedef uint32_t u32a  __attribute__((may_alias));
typedef uint2    u2a   __attribute__((may_alias));
typedef uint4    u4a   __attribute__((may_alias));

#define VS 2064   // Vt row stride in elements (2048 + 16: breaks 4KB L2 aliasing)

__device__ __forceinline__ ushort f2b(float f) {
  uint32_t u = __builtin_bit_cast(uint32_t, f);
  u += 0x7FFFu + ((u >> 16) & 1u);   // round-to-nearest-even
  return (ushort)(u >> 16);
}
__device__ __forceinline__ uint32_t b16(uint32_t u) {  // fp32 bits -> bf16 bits (RNE)
  u += 0x7FFFu + ((u >> 16) & 1u);
  return u >> 16;
}

__device__ __forceinline__ bf16x8 ld_frag(const ushort* p) {
  u4a u = *(const u4a*)p;            // ds_read_b128
  return __builtin_bit_cast(bf16x8, u);
}

// 8 fp32 -> 8 bf16 packed (two dwordx4 loads + RNE pack)
__device__ __forceinline__ u4a cvt8(const float* p) {
  u4a a = *(const u4a*)p, b = *(const u4a*)(p + 4), o;
  o.x = b16(a.x) | (b16(a.y) << 16);
  o.y = b16(a.z) | (b16(a.w) << 16);
  o.z = b16(b.x) | (b16(b.y) << 16);
  o.w = b16(b.z) | (b16(b.w) << 16);
  return o;
}

__device__ __forceinline__ void load_lds16(const void* g, void* l) {
  __builtin_amdgcn_global_load_lds(
      (const __attribute__((address_space(1))) uint32_t*)g,
      (__attribute__((address_space(3))) uint32_t*)l, 16, 0, 0);
}

// combine two packed bf16 pairs with weights w0,w1, repack
__device__ __forceinline__ uint32_t comb2(uint32_t a, uint32_t b, float w0, float w1) {
  float lo = __builtin_bit_cast(float, a << 16) * w0 +
             __builtin_bit_cast(float, b << 16) * w1;
  float hi = __builtin_bit_cast(float, a & 0xFFFF0000u) * w0 +
             __builtin_bit_cast(float, b & 0xFFFF0000u) * w1;
  return (uint32_t)f2b(lo) | ((uint32_t)f2b(hi) << 16);
}

// ---------------------------------------------------------------------------
// fp32 -> bf16 one-shot convert: x (3145728) then wq/wk/wv/wo (589824 each).
// ---------------------------------------------------------------------------
__global__ __launch_bounds__(256) void convert_kernel(
    const float* __restrict__ x,  const float* __restrict__ wq,
    const float* __restrict__ wk, const float* __restrict__ wv,
    const float* __restrict__ wo,
    ushort* __restrict__ xb,  ushort* __restrict__ wqb,
    ushort* __restrict__ wkb, ushort* __restrict__ wvb,
    ushort* __restrict__ wob)
{
  const size_t NX = 3145728, NW = 589824;
  size_t idx = ((size_t)blockIdx.x * 256 + threadIdx.x) * 8;
  const float* src; ushort* dst; size_t off;
  if      (idx < NX)          { src = x;  dst = xb;  off = idx; }
  else if (idx < NX + NW)     { src = wq; dst = wqb; off = idx - NX; }
  else if (idx < NX + 2 * NW) { src = wk; dst = wkb; off = idx - NX - NW; }
  else if (idx < NX + 3 * NW) { src = wv; dst = wvb; off = idx - NX - 2 * NW; }
  else                        { src = wo; dst = wob; off = idx - NX - 3 * NW; }
  *(u4a*)(dst + off) = cvt8(src + off);
}

// ---------------------------------------------------------------------------
// QKV: C[M,N]=A[M,K]*B[N,K]^T, bf16, fp32 acc. BM=128 BN=64 BK=32, 256 thr.
// grid (32, 12, 3): y-tile == one head. z: 0->Q, 1->K row-major; 2->V written
// transposed to Vt[b][h][dv][s] (stride VS).
// ---------------------------------------------------------------------------
__global__ __launch_bounds__(256) void gemm_qkv(
    const ushort* __restrict__ A,
    const ushort* __restrict__ B0, const ushort* __restrict__ B1,
    const ushort* __restrict__ B2,
    ushort* __restrict__ Qo, ushort* __restrict__ Ko, ushort* __restrict__ Vt,
    int M, int N, int K)
{
  const ushort* B = blockIdx.z == 0 ? B0 : (blockIdx.z == 1 ? B1 : B2);
  const int m0 = blockIdx.x * 128, n0 = blockIdx.y * 64;
  __shared__ ushort As[128 * 32];   // linear chunk order (global_load_lds layout)
  __shared__ ushort Bs[64 * 32];
  const int tid = threadIdx.x, wave = tid >> 6, lane = tid & 63;
  const int quad = lane >> 4, l16 = lane & 15;
  const int mw = (wave & 1) * 64, nw = (wave >> 1) * 32;
  f32x4 acc[4][2] = {};

  for (int k0 = 0; k0 < K; k0 += 32) {
    // A: 512 chunks of 16B (2/thread); B: 256 chunks (1/thread)
#pragma unroll
    for (int i = 0; i < 2; ++i) {
      int c = i * 256 + tid;
      load_lds16(A + (size_t)(m0 + (c >> 2)) * K + k0 + (c & 3) * 8,
                 As + (size_t)(i * 256 + wave * 64) * 8);
    }
    load_lds16(B + (size_t)(n0 + (tid >> 2)) * K + k0 + (tid & 3) * 8,
               Bs + (size_t)(wave * 64) * 8);
    __syncthreads();
    bf16x8 af[4], bfr[2];
#pragma unroll
    for (int i = 0; i < 4; ++i) af[i]  = ld_frag(As + (mw + i * 16 + l16) * 32 + quad * 8);
#pragma unroll
    for (int j = 0; j < 2; ++j) bfr[j] = ld_frag(Bs + (nw + j * 16 + l16) * 32 + quad * 8);
#pragma unroll
    for (int i = 0; i < 4; ++i)
#pragma unroll
      for (int j = 0; j < 2; ++j)
        acc[i][j] = __builtin_amdgcn_mfma_f32_16x16x32_bf16(af[i], bfr[j], acc[i][j], 0, 0, 0);
    __syncthreads();
  }
  // C/D layout: col=lane&15 (N), row=quad*4+reg (M)
  if (blockIdx.z < 2) {
    ushort* C = blockIdx.z == 0 ? Qo : Ko;
#pragma unroll
    for (int i = 0; i < 4; ++i)
#pragma unroll
      for (int j = 0; j < 2; ++j)
#pragma unroll
        for (int r = 0; r < 4; ++r) {
          int row = m0 + mw + i * 16 + quad * 4 + r;
          int col = n0 + nw + j * 16 + l16;
          C[(size_t)row * N + col] = f2b(acc[i][j][r]);
        }
  } else {
    // Vt[b][h][dv][s] (stride VS): h == blockIdx.y, dv = col&63
#pragma unroll
    for (int i = 0; i < 4; ++i)
#pragma unroll
      for (int j = 0; j < 2; ++j) {
        int col = n0 + nw + j * 16 + l16;
        int h = col >> 6, dv = col & 63;
        int t = m0 + mw + i * 16 + quad * 4;
        int b = t >> 11, s = t & 2047;
        u2a pw;
        pw.x = (uint32_t)f2b(acc[i][j][0]) | ((uint32_t)f2b(acc[i][j][1]) << 16);
        pw.y = (uint32_t)f2b(acc[i][j][2]) | ((uint32_t)f2b(acc[i][j][3]) << 16);
        *(u2a*)(Vt + (((size_t)b * 12 + h) * 64 + dv) * VS + s) = pw;
      }
  }
}

// ---------------------------------------------------------------------------
// Output projection: C[M,N](fp32) = A[M,K](bf16)*B[N,K]^T(bf16).
// BM=BN=64, BK=32, 256 thr, grid (64,12) = 768 blocks (3/CU).
// ---------------------------------------------------------------------------
__global__ __launch_bounds__(256) void gemm_out(
    const ushort* __restrict__ A, const ushort* __restrict__ B,
    float* __restrict__ C, int M, int N, int K)
{
  const int m0 = blockIdx.x * 64, n0 = blockIdx.y * 64;
  __shared__ ushort As[64 * 32];
  __shared__ ushort Bs[64 * 32];
  const int tid = threadIdx.x, wave = tid >> 6, lane = tid & 63;
  const int quad = lane >> 4, l16 = lane & 15;
  const int mw = (wave & 1) * 32, nw = (wave >> 1) * 32;
  f32x4 acc[2][2] = {};

  for (int k0 = 0; k0 < K; k0 += 32) {
    load_lds16(A + (size_t)(m0 + (tid >> 2)) * K + k0 + (tid & 3) * 8,
               As + (size_t)(wave * 64) * 8);
    load_lds16(B + (size_t)(n0 + (tid >> 2)) * K + k0 + (tid & 3) * 8,
               Bs + (size_t)(wave * 64) * 8);
    __syncthreads();
    bf16x8 af[2], bfr[2];
#pragma unroll
    for (int i = 0; i < 2; ++i) af[i]  = ld_frag(As + (mw + i * 16 + l16) * 32 + quad * 8);
#pragma unroll
    for (int j = 0; j < 2; ++j) bfr[j] = ld_frag(Bs + (nw + j * 16 + l16) * 32 + quad * 8);
#pragma unroll
    for (int i = 0; i < 2; ++i)
#pragma unroll
      for (int j = 0; j < 2; ++j)
        acc[i][j] = __builtin_amdgcn_mfma_f32_16x16x32_bf16(af[i], bfr[j], acc[i][j], 0, 0, 0);
    __syncthreads();
  }
#pragma unroll
  for (int i = 0; i < 2; ++i)
#pragma unroll
    for (int j = 0; j < 2; ++j)
#pragma unroll
      for (int r = 0; r < 4; ++r) {
        int row = m0 + mw + i * 16 + quad * 4 + r;
        int col = n0 + nw + j * 16 + l16;
        C[(size_t)row * N + col] = acc[i][j][r];
      }
}

// ---------------------------------------------------------------------------
// Causal flash attention, K-SPLIT + pair-balanced: grid (32,12,2);
// x = pair*2 + j. Block handles q-tiles {p, 31-p}, K-tiles kt ≡ j (mod 2)
// -> 768 perfectly uniform sub-blocks (~8.5 K-tile units each).
// Emits unnormalized partials: Opart bf16[64][64], ML=(m,l) f32 per q-row.
// ---------------------------------------------------------------------------
__global__ __launch_bounds__(256) void attn_kernel(
    const ushort* __restrict__ Qb, const ushort* __restrict__ Kb,
    const ushort* __restrict__ Vt, ushort* __restrict__ Opart,
    float2* __restrict__ MLp)
{
  const int S = 2048, DM = 768;
  const int pair = blockIdx.x >> 1, j = blockIdx.x & 1;
  const int h = blockIdx.y, bb = blockIdx.z;
  const ushort* Qp  = Qb + (size_t)bb * S * DM + h * 64;
  const ushort* Kp  = Kb + (size_t)bb * S * DM + h * 64;
  const ushort* Vth = Vt + ((size_t)bb * 12 + h) * 64 * VS;   // [dv][s]

  __shared__ ushort Ks[128 * 72];     // [kk][dk], pad 64->72
  __shared__ ushort Vs[64 * 136];     // [dv][kk], pad 128->136
  __shared__ ushort Ps[4][16 * 136];  // per-wave P[q][kk], pad 128->136

  const int tid = threadIdx.x, wave = tid >> 6, lane = tid & 63;
  const int quad = lane >> 4, l16 = lane & 15;
  const float LOG2E = 1.44269504f;
  const float NEG_BIG = -1.0e30f;

  for (int sp = 0; sp < 2; ++sp) {
    const int qt = sp == 0 ? pair : 31 - pair;
    const int q0 = qt * 64;
    const int qg = q0 + wave * 16 + l16;   // this lane's q row

    // Q fragments (B operand of S^T = K*Q^T)
    bf16x8 bq0 = ld_frag(Qp + (size_t)qg * DM + quad * 8);
    bf16x8 bq1 = ld_frag(Qp + (size_t)qg * DM + 32 + quad * 8);

    f32x4 acc_o[4] = {};
    float m_run = NEG_BIG, l_run = 0.0f;
    const int nkt = (qt >> 1) + 1;

    for (int kt = j; kt < nkt; kt += 2) {
      const int kk0 = kt * 128;
      // stage K tile: chunk c -> row c>>3, col (c&7)*8
#pragma unroll
      for (int i = 0; i < 4; ++i) {
        int c = i * 256 + tid;
        int r = c >> 3, col = (c & 7) * 8;
        *(u4a*)(Ks + r * 72 + col) = *(const u4a*)(Kp + (size_t)(kk0 + r) * DM + col);
      }
      // stage V tile from Vt: chunk c -> dv c>>4, kk (c&15)*8
#pragma unroll
      for (int i = 0; i < 4; ++i) {
        int c = i * 256 + tid;
        int dv = c >> 4, kc = (c & 15) * 8;
        *(u4a*)(Vs + dv * 136 + kc) = *(const u4a*)(Vth + (size_t)dv * VS + kk0 + kc);
      }
      __syncthreads();

      // S^T strip: this wave's 16 q cols x 128 kk rows = 8 tiles
      f32x4 sacc[8] = {};
#pragma unroll
      for (int tt = 0; tt < 8; ++tt) {
        bf16x8 ak0 = ld_frag(Ks + (tt * 16 + l16) * 72 + quad * 8);
        bf16x8 ak1 = ld_frag(Ks + (tt * 16 + l16) * 72 + 32 + quad * 8);
        sacc[tt] = __builtin_amdgcn_mfma_f32_16x16x32_bf16(ak0, bq0, sacc[tt], 0, 0, 0);
        sacc[tt] = __builtin_amdgcn_mfma_f32_16x16x32_bf16(ak1, bq1, sacc[tt], 0, 0, 0);
      }

      // scale + causal mask (only the diagonal tile needs it)
      const bool domask = (kt == nkt - 1);
      float sv[8][4];
      float mt = NEG_BIG;
#pragma unroll
      for (int tt = 0; tt < 8; ++tt)
#pragma unroll
        for (int r = 0; r < 4; ++r) {
          float s = sacc[tt][r] * 0.125f;   // 1/sqrt(64)
          if (domask) {
            int kkg = kk0 + tt * 16 + quad * 4 + r;
            if (kkg > qg) s = NEG_BIG;
          }
          sv[tt][r] = s;
          mt = fmaxf(mt, s);
        }
      mt = fmaxf(mt, __shfl_xor(mt, 16, 64));
      mt = fmaxf(mt, __shfl_xor(mt, 32, 64));
      float mnew = fmaxf(m_run, mt);
      float alpha = exp2f((m_run - mnew) * LOG2E);
      float lsum = 0.0f;
#pragma unroll
      for (int tt = 0; tt < 8; ++tt) {
        float p0 = exp2f((sv[tt][0] - mnew) * LOG2E);
        float p1 = exp2f((sv[tt][1] - mnew) * LOG2E);
        float p2 = exp2f((sv[tt][2] - mnew) * LOG2E);
        float p3 = exp2f((sv[tt][3] - mnew) * LOG2E);
        lsum += (p0 + p1) + (p2 + p3);
        u2a pw;
        pw.x = (uint32_t)f2b(p0) | ((uint32_t)f2b(p1) << 16);
        pw.y = (uint32_t)f2b(p2) | ((uint32_t)f2b(p3) << 16);
        *(u2a*)(&Ps[wave][l16 * 136 + tt * 16 + quad * 4]) = pw;
      }
      // Ps is per-wave: drain own LDS writes, forbid compile-time reordering.
      asm volatile("s_waitcnt lgkmcnt(0)" ::: "memory");
      lsum += __shfl_xor(lsum, 16, 64);
      lsum += __shfl_xor(lsum, 32, 64);
      l_run = l_run * alpha + lsum;
      m_run = mnew;

      // rescale O: O rows are q = quad*4+reg, alpha lives at lane l16==q
      float ar0 = __shfl(alpha, quad * 4 + 0, 64);
      float ar1 = __shfl(alpha, quad * 4 + 1, 64);
      float ar2 = __shfl(alpha, quad * 4 + 2, 64);
      float ar3 = __shfl(alpha, quad * 4 + 3, 64);
#pragma unroll
      for (int ct = 0; ct < 4; ++ct) {
        acc_o[ct][0] *= ar0; acc_o[ct][1] *= ar1;
        acc_o[ct][2] *= ar2; acc_o[ct][3] *= ar3;
      }

      // O += P*V
#pragma unroll
      for (int ks = 0; ks < 4; ++ks) {
        bf16x8 ap = ld_frag(&Ps[wave][l16 * 136 + ks * 32 + quad * 8]);
#pragma unroll
        for (int ct = 0; ct < 4; ++ct) {
          bf16x8 bv = ld_frag(Vs + (size_t)(ct * 16 + l16) * 136 + ks * 32 + quad * 8);
          acc_o[ct] = __builtin_amdgcn_mfma_f32_16x16x32_bf16(ap, bv, acc_o[ct], 0, 0, 0);
        }
      }
      __syncthreads();   // protect Ks/Vs before next restage
    }

    // store unnormalized partial (bf16 O + per-row m,l)
    const int slot = (((bb * 12 + h) << 5) + qt) * 2 + j;
    ushort* Os = Opart + (size_t)slot * 4096;
    const int r0 = wave * 16 + quad * 4;
#pragma unroll
    for (int ct = 0; ct < 4; ++ct) {
      int col = ct * 16 + l16;
      Os[(r0 + 0) * 64 + col] = f2b(acc_o[ct][0]);
      Os[(r0 + 1) * 64 + col] = f2b(acc_o[ct][1]);
      Os[(r0 + 2) * 64 + col] = f2b(acc_o[ct][2]);
      Os[(r0 + 3) * 64 + col] = f2b(acc_o[ct][3]);
    }
    if (quad == 0)
      MLp[(size_t)slot * 64 + wave * 16 + l16] = make_float2(m_run, l_run);
  }
}

// ---------------------------------------------------------------------------
// Combine the two K-parity partials per strip -> Abuf (b, s, h*64) bf16.
// grid 768 (one block per strip), 256 threads, 16 elems/thread.
// ---------------------------------------------------------------------------
__global__ __launch_bounds__(256) void combine_kernel(
    const ushort* __restrict__ Opart, const float2* __restrict__ MLp,
    ushort* __restrict__ Ab)
{
  const int sid = blockIdx.x;
  const int bb = sid / 384, rem = sid % 384, h = rem >> 5, qt = rem & 31;
  const int t = threadIdx.x, row = t >> 2, cg = (t & 3) * 16;
  float2 ml0 = MLp[(size_t)(sid * 2) * 64 + row];
  float2 ml1 = MLp[(size_t)(sid * 2 + 1) * 64 + row];
  float ms = fmaxf(ml0.x, ml1.x);
  float w0 = exp2f((ml0.x - ms) * 1.44269504f);
  float w1 = exp2f((ml1.x - ms) * 1.44269504f);
  float inv = 1.0f / (ml0.y * w0 + ml1.y * w1);
  w0 *= inv; w1 *= inv;
  const ushort* p0 = Opart + (size_t)(sid * 2) * 4096 + row * 64 + cg;
  ushort* dst = Ab + ((size_t)(bb * 2048 + qt * 64 + row)) * 768 + h * 64 + cg;
#pragma unroll
  for (int g = 0; g < 2; ++g) {
    u4a a = *(const u4a*)(p0 + g * 8);
    u4a b = *(const u4a*)(p0 + 4096 + g * 8);
    u4a o;
    o.x = comb2(a.x, b.x, w0, w1);
    o.y = comb2(a.y, b.y, w0, w1);
    o.z = comb2(a.z, b.z, w0, w1);
    o.w = comb2(a.w, b.w, w0, w1);
    *(u4a*)(dst + g * 8) = o;
  }
}

// ---------------------------------------------------------------------------
extern "C" void kernel_launch(void* const* d_in, const int* in_sizes, int n_in,
                              void* d_out, int out_size, void* d_ws, size_t ws_size,
                              hipStream_t stream) {
  (void)in_sizes; (void)n_in; (void)out_size; (void)ws_size;
  const float* x  = (const float*)d_in[0];
  const float* wq = (const float*)d_in[1];
  const float* wk = (const float*)d_in[2];
  const float* wv = (const float*)d_in[3];
  const float* wo = (const float*)d_in[4];

  const size_t NT = (size_t)4096 * 768;   // tokens x d_model
  const size_t NW = (size_t)768 * 768;
  const size_t NV = (size_t)24 * 64 * VS; // padded Vt
  ushort* xb    = (ushort*)d_ws;          // reused as Abuf after QKV GEMM
  ushort* Qbuf  = xb + NT;
  ushort* Kbuf  = Qbuf + NT;
  ushort* Vt    = Kbuf + NT;              // (b, h, dv, s) stride VS
  ushort* wqb   = Vt + NV;
  ushort* wkb   = wqb + NW;
  ushort* wvb   = wkb + NW;
  ushort* wob   = wvb + NW;
  ushort* Opart = wob + NW;               // 1536 x 64 x 64 bf16
  float2* MLp   = (float2*)(Opart + (size_t)1536 * 4096);  // 1536 x 64
  ushort* Abuf  = xb;                     // lifetime-disjoint reuse

  // fp32 -> bf16 (x + all weights)
  convert_kernel<<<2688, 256, 0, stream>>>(x, wq, wk, wv, wo,
                                           xb, wqb, wkb, wvb, wob);
  // Q/K/V projections (z picks weight & dest; V lands transposed in Vt)
  gemm_qkv<<<dim3(32, 12, 3), 256, 0, stream>>>(
      xb, wqb, wkb, wvb, Qbuf, Kbuf, Vt, 4096, 768, 768);
  // causal flash attention: 768 uniform K-split sub-blocks -> partials
  attn_kernel<<<dim3(32, 12, 2), 256, 0, stream>>>(Qbuf, Kbuf, Vt, Opart, MLp);
  // merge partials -> Abuf
  combine_kernel<<<768, 256, 0, stream>>>(Opart, MLp, Abuf);
  // output projection (fp32 out)
  gemm_out<<<dim3(64, 12), 256, 0, stream>>>(
      Abuf, wob, (float*)d_out, 4096, 768, 768);
}